// Round 11
// baseline (253.720 us; speedup 1.0000x reference)
//
#include <hip/hip_runtime.h>
#include <hip/hip_bf16.h>
#include <cstdint>
#include <cstddef>

typedef short bf16x8 __attribute__((ext_vector_type(8)));
typedef float f32x16 __attribute__((ext_vector_type(16)));
typedef unsigned int uint2v __attribute__((ext_vector_type(2)));

#if __has_builtin(__builtin_amdgcn_exp2f)
#define EXP2F(x) __builtin_amdgcn_exp2f(x)
#else
#define EXP2F(x) exp2f(x)
#endif

// scale^2 * log2(e) folded into Q; ch=64 -> (1/8)*1.4426950408889634
#define QSCALE 0.18033688011112043f

__device__ __forceinline__ short f2bf(float f) {
  union { __hip_bfloat16 b; short s; } u;
  u.b = __float2bfloat16(f);
  return u.s;
}

__device__ __forceinline__ unsigned int fbits(float f) {
  union { float f; unsigned int u; } x; x.f = f; return x.u;
}
__device__ __forceinline__ float bfloat(unsigned int u) {
  union { unsigned int u; float f; } x; x.u = u; return x.f;
}

// fast packed f32x2 -> bf16x2, round-half-up (R5-verified on softmax P)
__device__ __forceinline__ unsigned int pkbf(float a, float b) {
  return ((fbits(a) + 0x8000u) >> 16) | ((fbits(b) + 0x8000u) & 0xFFFF0000u);
}

// permlane32_swap builtin — ONLY for commutative own+partner combines
// (correct under any half-swap convention; results contain {own,partner})
__device__ __forceinline__ float fmax_x32(float v) {
  const uint2v r = __builtin_amdgcn_permlane32_swap(fbits(v), fbits(v),
                                                    false, false);
  return fmaxf(bfloat(r[0]), bfloat(r[1]));
}
__device__ __forceinline__ float fadd_x32(float v) {
  const uint2v r = __builtin_amdgcn_permlane32_swap(fbits(v), fbits(v),
                                                    false, false);
  return bfloat(r[0]) + bfloat(r[1]);
}

// ---------------------------------------------------------------------------
// Prepass: Kt[bh][s][c] = bf16(K[c][s]);  Vb[bh][c][s] = bf16(V[c][s]).
// qkv layout: [bh][cc][t], cc: 0..63 Q, 64..127 K, 128..191 V.
// ---------------------------------------------------------------------------
__global__ __launch_bounds__(256, 4) void qkv_prep_kernel(
    const float* __restrict__ qkv, short* __restrict__ Kt,
    short* __restrict__ Vb) {
  const int bh = blockIdx.x >> 5;
  const int s0 = (blockIdx.x & 31) << 6;
  const int tid = threadIdx.x;
  const int row = tid >> 2;   // 0..63
  const int part = tid & 3;   // 0..3  (16 columns each)
  __shared__ float lds[64 * 65];

  const size_t qb = (size_t)bh * (192 * 2048);

  // ---- K: load [c][s] tile coalesced into LDS ----
  {
    const float* src = qkv + qb + (size_t)(64 + row) * 2048 + s0 + part * 16;
#pragma unroll
    for (int k4 = 0; k4 < 4; ++k4) {
      float4 v = ((const float4*)src)[k4];
      float* p = &lds[row * 65 + part * 16 + k4 * 4];
      p[0] = v.x; p[1] = v.y; p[2] = v.z; p[3] = v.w;
    }
  }
  __syncthreads();
  // ---- transposed read -> Kt[s][c], coalesced 16B stores ----
  {
    bf16x8 o0, o1;
#pragma unroll
    for (int k = 0; k < 8; ++k) o0[k] = f2bf(lds[(part * 16 + k) * 65 + row]);
#pragma unroll
    for (int k = 0; k < 8; ++k) o1[k] = f2bf(lds[(part * 16 + 8 + k) * 65 + row]);
    short* dst = Kt + ((size_t)bh * 2048 + s0 + row) * 64 + part * 16;
    *(bf16x8*)dst = o0;
    *(bf16x8*)(dst + 8) = o1;
  }
  // ---- V: straight convert, both sides coalesced ----
  {
    const float* src = qkv + qb + (size_t)(128 + row) * 2048 + s0 + part * 16;
    float a[16];
#pragma unroll
    for (int k4 = 0; k4 < 4; ++k4) {
      float4 v = ((const float4*)src)[k4];
      a[k4 * 4 + 0] = v.x; a[k4 * 4 + 1] = v.y;
      a[k4 * 4 + 2] = v.z; a[k4 * 4 + 3] = v.w;
    }
    bf16x8 o0, o1;
#pragma unroll
    for (int k = 0; k < 8; ++k) { o0[k] = f2bf(a[k]); o1[k] = f2bf(a[8 + k]); }
    short* dst = Vb + ((size_t)bh * 64 + row) * 2048 + s0 + part * 16;
    *(bf16x8*)dst = o0;
    *(bf16x8*)(dst + 8) = o1;
  }
}

// ---------------------------------------------------------------------------
// Flash attention, LDS-FREE: K and V MFMA fragments loaded directly from
// global (L2/L1-resident: per-XCD working set = 8 bh x 512 KB; XCD swizzle
// pins each bh's 16 blocks to one XCD). No __shared__, no barriers — waves
// fully independent, so VALU / VMEM / MFMA phases of different waves
// overlap freely (m114), instead of block-lockstep phase serialization.
// Every fragment is a naturally-aligned 16B load:
//   K: Kt[bh][s = st*32+tl + 64*ch][c = kc*16 + hi*8 + j]
//   V: Vb[bh][c = cb*32+tl][s = 64*ch + ks*16 + hi*8 + j]
// Compute path (QK swapped, per-lane softmax, pkbf pack, shfl redistribute,
// PV, epilogue) is byte-identical to R9/R10-verified code.
// ---------------------------------------------------------------------------
__global__ __launch_bounds__(256, 4) void attn32_kernel(
    const float* __restrict__ qkv, const short* __restrict__ Kt,
    const short* __restrict__ Vb, float* __restrict__ out) {
  const int bid = blockIdx.x;
  const int vid = (bid & 7) * 128 + (bid >> 3);  // bijective XCD swizzle
  const int bh = vid >> 4;
  const int tblk = vid & 15;
  const int tid = threadIdx.x;
  const int wv = tid >> 6;          // 0..3
  const int lane = tid & 63;
  const int tl = lane & 31;
  const int hi = lane >> 5;
  const int t0w = tblk * 128 + wv * 32;

  // ---- Q fragments (B-operand: col = t = lane&31, k = kc*16 + hi*8 + j) ----
  const size_t qb = (size_t)bh * (192 * 2048);
  bf16x8 qf[4];
#pragma unroll
  for (int kc = 0; kc < 4; ++kc) {
#pragma unroll
    for (int j = 0; j < 8; ++j) {
      const int c = kc * 16 + hi * 8 + j;
      qf[kc][j] = f2bf(qkv[qb + (size_t)c * 2048 + t0w + tl] * QSCALE);
    }
  }

  // persistent zero C-operand (avoids per-chunk zero-init movs)
  f32x16 zv;
#pragma unroll
  for (int r = 0; r < 16; ++r) zv[r] = 0.f;

  f32x16 acc[2];
#pragma unroll
  for (int cb = 0; cb < 2; ++cb) acc[cb] = zv;

  float mrun = -1e30f;
  float lsum = 0.f;

  // ---- per-lane global fragment base pointers ----
  // K rows (s): st*32+tl ; k-slice byte offset kc*16 elems + hi*8
  const short* kp0 = Kt + (size_t)bh * (2048 * 64) + (size_t)tl * 64 + hi * 8;
  const short* kp1 = kp0 + 32 * 64;
  // V rows (c): cb*32+tl ; s-slice offset ks*16 elems + hi*8
  const short* vp0 = Vb + ((size_t)bh * 64 + tl) * 2048 + hi * 8;
  const short* vp1 = vp0 + (size_t)32 * 2048;

  for (int ch = 0; ch < 32; ++ch) {
    const size_t kofs = (size_t)ch * 4096;   // 64 s-rows x 64 c
    const int sofs = ch * 64;                // 64 s along a V row

    // ---- QK^T: two 32-s tiles, A = K (rows=s), B = Q (cols=t) ----
    f32x16 lg[2];
#pragma unroll
    for (int st = 0; st < 2; ++st) {
      const short* kp = st ? kp1 : kp0;
      bf16x8 ka = *(const bf16x8*)(kp + kofs);
      lg[st] = __builtin_amdgcn_mfma_f32_32x32x16_bf16(ka, qf[0], zv, 0, 0, 0);
#pragma unroll
      for (int kc = 1; kc < 4; ++kc) {
        ka = *(const bf16x8*)(kp + kofs + kc * 16);
        lg[st] = __builtin_amdgcn_mfma_f32_32x32x16_bf16(ka, qf[kc], lg[st],
                                                         0, 0, 0);
      }
    }

    // ---- online max: max3-shaped tree + permlane cross-half ----
    float w[11];
#pragma unroll
    for (int i = 0; i < 5; ++i)
      w[i] = fmaxf(fmaxf(lg[0][3 * i], lg[0][3 * i + 1]), lg[0][3 * i + 2]);
    w[5] = fmaxf(fmaxf(lg[0][15], lg[1][0]), lg[1][1]);
#pragma unroll
    for (int i = 0; i < 4; ++i)
      w[6 + i] = fmaxf(fmaxf(lg[1][3 * i + 2], lg[1][3 * i + 3]),
                       lg[1][3 * i + 4]);
    w[10] = fmaxf(lg[1][14], lg[1][15]);
    const float x0 = fmaxf(fmaxf(w[0], w[1]), w[2]);
    const float x1 = fmaxf(fmaxf(w[3], w[4]), w[5]);
    const float x2 = fmaxf(fmaxf(w[6], w[7]), w[8]);
    const float x3 = fmaxf(w[9], w[10]);
    float cm = fmax_x32(fmaxf(fmaxf(x0, x1), fmaxf(x2, x3)));
    if (!__all(cm <= mrun + 8.0f)) {   // deferred rescale, THR=8 (log2)
      const float nm = fmaxf(mrun, cm);
      const float fac = EXP2F(mrun - nm);
      mrun = nm;
      lsum *= fac;
#pragma unroll
      for (int cb = 0; cb < 2; ++cb)
#pragma unroll
        for (int r = 0; r < 16; ++r) acc[cb][r] *= fac;
    }

    // ---- P = exp2(lg - m) in place; pairwise partial sum ----
    float ps = 0.f;
#pragma unroll
    for (int st = 0; st < 2; ++st) {
#pragma unroll
      for (int r = 0; r < 16; ++r) lg[st][r] = EXP2F(lg[st][r] - mrun);
#pragma unroll
      for (int r = 0; r < 8; ++r) ps += lg[st][2 * r] + lg[st][2 * r + 1];
    }
    lsum += ps;

    // ---- pack + redistribute P -> PV fragments pa[ks] (R5-verified) ----
    bf16x8 pa[4];
#pragma unroll
    for (int st = 0; st < 2; ++st) {
#pragma unroll
      for (int kl = 0; kl < 2; ++kl) {
        const unsigned int p0a = pkbf(lg[st][8 * kl + 0], lg[st][8 * kl + 1]);
        const unsigned int p0b = pkbf(lg[st][8 * kl + 2], lg[st][8 * kl + 3]);
        const unsigned int p1a = pkbf(lg[st][8 * kl + 4], lg[st][8 * kl + 5]);
        const unsigned int p1b = pkbf(lg[st][8 * kl + 6], lg[st][8 * kl + 7]);
        const unsigned int sa = hi ? p0a : p1a;
        const unsigned int sb = hi ? p0b : p1b;
        const unsigned int ra = __shfl_xor(sa, 32);
        const unsigned int rb = __shfl_xor(sb, 32);
        union { unsigned int w[4]; bf16x8 v; } u;
        u.w[0] = hi ? ra : p0a;   // k-offsets 0,1
        u.w[1] = hi ? rb : p0b;   // 2,3
        u.w[2] = hi ? p1a : ra;   // 4,5
        u.w[3] = hi ? p1b : rb;   // 6,7
        pa[st * 2 + kl] = u.v;
      }
    }

    // ---- PV: acc[cb] += V * P  (A = V rows=c, B = pa cols=t) ----
#pragma unroll
    for (int cb = 0; cb < 2; ++cb) {
      const short* vp = cb ? vp1 : vp0;
#pragma unroll
      for (int ks = 0; ks < 4; ++ks) {
        const bf16x8 vb = *(const bf16x8*)(vp + sofs + ks * 16);
        acc[cb] = __builtin_amdgcn_mfma_f32_32x32x16_bf16(vb, pa[ks], acc[cb],
                                                          0, 0, 0);
      }
    }
  }

  // ---- epilogue: normalize + store (D: col=t=lane&31, row=c) ----
  const float ls = fadd_x32(lsum);
  const float inv = 1.0f / ls;
#pragma unroll
  for (int cb = 0; cb < 2; ++cb) {
#pragma unroll
    for (int r = 0; r < 16; ++r) {
      const int c = cb * 32 + (r & 3) + 8 * (r >> 2) + 4 * hi;
      out[((size_t)bh * 64 + c) * 2048 + t0w + tl] = acc[cb][r] * inv;
    }
  }
}

extern "C" void kernel_launch(void* const* d_in, const int* in_sizes, int n_in,
                              void* d_out, int out_size, void* d_ws,
                              size_t ws_size, hipStream_t stream) {
  (void)in_sizes; (void)n_in; (void)out_size;
  const float* qkv = (const float*)d_in[0];
  float* out = (float*)d_out;
  const size_t kv_elems = (size_t)64 * 2048 * 64;
  if (ws_size < kv_elems * 2 * sizeof(short)) return;  // need 32 MB scratch
  short* Kt = (short*)d_ws;
  short* Vb = Kt + kv_elems;
  hipLaunchKernelGGL(qkv_prep_kernel, dim3(2048), dim3(256), 0, stream,
                     qkv, Kt, Vb);
  hipLaunchKernelGGL(attn32_kernel, dim3(1024), dim3(256), 0, stream,
                     qkv, Kt, Vb, out);
}

// Round 12
// 135.901 us; speedup vs baseline: 1.8669x; 1.8669x over previous
//
#include <hip/hip_runtime.h>
#include <hip/hip_bf16.h>
#include <cstdint>
#include <cstddef>

typedef short bf16x8 __attribute__((ext_vector_type(8)));
typedef float f32x16 __attribute__((ext_vector_type(16)));
typedef unsigned int uint2v __attribute__((ext_vector_type(2)));

#if __has_builtin(__builtin_amdgcn_exp2f)
#define EXP2F(x) __builtin_amdgcn_exp2f(x)
#else
#define EXP2F(x) exp2f(x)
#endif

// scale^2 * log2(e) folded into Q; ch=64 -> (1/8)*1.4426950408889634
#define QSCALE 0.18033688011112043f

__device__ __forceinline__ short f2bf(float f) {
  union { __hip_bfloat16 b; short s; } u;
  u.b = __float2bfloat16(f);
  return u.s;
}

__device__ __forceinline__ unsigned int fbits(float f) {
  union { float f; unsigned int u; } x; x.f = f; return x.u;
}
__device__ __forceinline__ float bfloat(unsigned int u) {
  union { unsigned int u; float f; } x; x.u = u; return x.f;
}

// fast packed f32x2 -> bf16x2, round-half-up (R5-verified on softmax P)
__device__ __forceinline__ unsigned int pkbf(float a, float b) {
  return ((fbits(a) + 0x8000u) >> 16) | ((fbits(b) + 0x8000u) & 0xFFFF0000u);
}

// permlane32_swap builtin — ONLY for commutative own+partner combines
// (correct under any half-swap convention; results contain {own,partner})
__device__ __forceinline__ float fmax_x32(float v) {
  const uint2v r = __builtin_amdgcn_permlane32_swap(fbits(v), fbits(v),
                                                    false, false);
  return fmaxf(bfloat(r[0]), bfloat(r[1]));
}
__device__ __forceinline__ float fadd_x32(float v) {
  const uint2v r = __builtin_amdgcn_permlane32_swap(fbits(v), fbits(v),
                                                    false, false);
  return bfloat(r[0]) + bfloat(r[1]);
}

// async global -> LDS, 16 B per lane; LDS dest = wave-uniform base + lane*16
__device__ __forceinline__ void gload16(const short* g, char* l) {
  __builtin_amdgcn_global_load_lds(
      (const __attribute__((address_space(1))) void*)g,
      (__attribute__((address_space(3))) void*)l, 16, 0, 0);
}

// ---------------------------------------------------------------------------
// Prepass: Kt[bh][s][c] = bf16(K[c][s]);  Vb[bh][c][s] = bf16(V[c][s]).
// qkv layout: [bh][cc][t], cc: 0..63 Q, 64..127 K, 128..191 V.
// ---------------------------------------------------------------------------
__global__ __launch_bounds__(256, 4) void qkv_prep_kernel(
    const float* __restrict__ qkv, short* __restrict__ Kt,
    short* __restrict__ Vb) {
  const int bh = blockIdx.x >> 5;
  const int s0 = (blockIdx.x & 31) << 6;
  const int tid = threadIdx.x;
  const int row = tid >> 2;   // 0..63
  const int part = tid & 3;   // 0..3  (16 columns each)
  __shared__ float lds[64 * 65];

  const size_t qb = (size_t)bh * (192 * 2048);

  // ---- K: load [c][s] tile coalesced into LDS ----
  {
    const float* src = qkv + qb + (size_t)(64 + row) * 2048 + s0 + part * 16;
#pragma unroll
    for (int k4 = 0; k4 < 4; ++k4) {
      float4 v = ((const float4*)src)[k4];
      float* p = &lds[row * 65 + part * 16 + k4 * 4];
      p[0] = v.x; p[1] = v.y; p[2] = v.z; p[3] = v.w;
    }
  }
  __syncthreads();
  // ---- transposed read -> Kt[s][c], coalesced 16B stores ----
  {
    bf16x8 o0, o1;
#pragma unroll
    for (int k = 0; k < 8; ++k) o0[k] = f2bf(lds[(part * 16 + k) * 65 + row]);
#pragma unroll
    for (int k = 0; k < 8; ++k) o1[k] = f2bf(lds[(part * 16 + 8 + k) * 65 + row]);
    short* dst = Kt + ((size_t)bh * 2048 + s0 + row) * 64 + part * 16;
    *(bf16x8*)dst = o0;
    *(bf16x8*)(dst + 8) = o1;
  }
  // ---- V: straight convert, both sides coalesced ----
  {
    const float* src = qkv + qb + (size_t)(128 + row) * 2048 + s0 + part * 16;
    float a[16];
#pragma unroll
    for (int k4 = 0; k4 < 4; ++k4) {
      float4 v = ((const float4*)src)[k4];
      a[k4 * 4 + 0] = v.x; a[k4 * 4 + 1] = v.y;
      a[k4 * 4 + 2] = v.z; a[k4 * 4 + 3] = v.w;
    }
    bf16x8 o0, o1;
#pragma unroll
    for (int k = 0; k < 8; ++k) { o0[k] = f2bf(a[k]); o1[k] = f2bf(a[8 + k]); }
    short* dst = Vb + ((size_t)bh * 64 + row) * 2048 + s0 + part * 16;
    *(bf16x8*)dst = o0;
    *(bf16x8*)(dst + 8) = o1;
  }
}

// ---------------------------------------------------------------------------
// Flash attention, paired-chunk pipeline. 512 blocks (XCD-swizzled), 8 waves,
// wave owns 32 t. s processed in 16 phases of 128 (two 64-s sub-chunks A,B).
// Per phase (ONE barrier):  stage next phase (4 gload_lds, async) ->
//   QK_A ; QK_B ; SM_A ; PV_A ; SM_B ; PV_B
// QK_B is data-independent of SM_A, PV_A independent of SM_B -> the
// scheduler can overlap MFMA/DS of one sub-chunk with VALU of the other
// (within-wave m114 overlap). Sequential SM_A-then-SM_B updates of
// (mrun,lsum,acc) are semantically identical to R10's per-chunk updates.
// LDS 64 KB dbuf: [buf][K_A|K_B|V_A|V_B][8 KB], each sub-tile = R10-verified
// [64 rows][128B] layout, pre-swizzled global source, swizzled reads.
// ---------------------------------------------------------------------------
__global__ __launch_bounds__(512, 4) void attn32_kernel(
    const float* __restrict__ qkv, const short* __restrict__ Kt,
    const short* __restrict__ Vb, float* __restrict__ out) {
  const int bid = blockIdx.x;
  const int vid = (bid & 7) * 64 + (bid >> 3);  // bijective XCD swizzle (512)
  const int bh = vid >> 3;
  const int tblk = vid & 7;
  const int tid = threadIdx.x;
  const int wv = tid >> 6;          // 0..7
  const int lane = tid & 63;
  const int tl = lane & 31;
  const int hi = lane >> 5;
  const int t0w = tblk * 256 + wv * 32;

  // [buf0: KA|KB|VA|VB][buf1: KA|KB|VA|VB], 8 KB each sub-tile
  __shared__ __align__(16) char smem[65536];

  // ---- Q fragments (B-operand: col = t = lane&31, k = kc*16 + hi*8 + j) ----
  const size_t qb = (size_t)bh * (192 * 2048);
  bf16x8 qf[4];
#pragma unroll
  for (int kc = 0; kc < 4; ++kc) {
#pragma unroll
    for (int j = 0; j < 8; ++j) {
      const int c = kc * 16 + hi * 8 + j;
      qf[kc][j] = f2bf(qkv[qb + (size_t)c * 2048 + t0w + tl] * QSCALE);
    }
  }

  // persistent zero C-operand (avoids per-chunk zero-init movs)
  f32x16 zv;
#pragma unroll
  for (int r = 0; r < 16; ++r) zv[r] = 0.f;

  f32x16 acc[2];
#pragma unroll
  for (int cb = 0; cb < 2; ++cb) acc[cb] = zv;

  float mrun = -1e30f;
  float lsum = 0.f;

  // ---- hoisted LDS read offsets (serve QK rows=s and PV rows=c) ----
  const int rsw = (tl & 7) * 16;
  int off[2][4];
#pragma unroll
  for (int x = 0; x < 2; ++x)
#pragma unroll
    for (int j = 0; j < 4; ++j)
      off[x][j] = (x * 32 + tl) * 128 + ((j * 32 + hi * 16) ^ rsw);

  // ---- staging geometry (R10-verified): 512 threads cover 64 rows ----
  const int srow = tid >> 3;   // 0..63
  const int sl = tid & 7;      // 16B slot within 128B row
  const short* kg = Kt + (size_t)bh * (2048 * 64) + (size_t)srow * 64 +
                    ((sl ^ (srow & 7)) * 8);
  const short* vg = Vb + ((size_t)bh * 64 + srow) * 2048 +
                    ((sl ^ (srow & 7)) * 8);
  const int ldb = wv * 1024;   // wave covers rows [wv*8, wv*8+8)

  // ---- prologue: stage phase 0 (chunks 0,1) into buf0 ----
  gload16(kg, smem + 0 * 8192 + ldb);
  gload16(kg + 4096, smem + 1 * 8192 + ldb);
  gload16(vg, smem + 2 * 8192 + ldb);
  gload16(vg + 64, smem + 3 * 8192 + ldb);

  for (int p = 0; p < 16; ++p) {
    char* const base = smem + (p & 1) * 32768;

    // barrier: waves done reading buf^1, vmcnt(0) drains this phase's stage
    __syncthreads();

    // ---- stage next phase (chunks 2p+2, 2p+3); flies under compute ----
    if (p < 15) {
      char* const nb = smem + ((p + 1) & 1) * 32768;
      const size_t k0 = (size_t)(2 * p + 2) * 4096;
      const int v0 = (2 * p + 2) * 64;
      gload16(kg + k0, nb + 0 * 8192 + ldb);
      gload16(kg + k0 + 4096, nb + 1 * 8192 + ldb);
      gload16(vg + v0, nb + 2 * 8192 + ldb);
      gload16(vg + v0 + 64, nb + 3 * 8192 + ldb);
    }

    // ---- QK_A and QK_B (independent; B's MFMAs overlap A's softmax) ----
    f32x16 lgA[2], lgB[2];
#pragma unroll
    for (int st = 0; st < 2; ++st) {
      const char* Kls = base;  // K_A
      bf16x8 ka = *(const bf16x8*)(Kls + off[st][0]);
      lgA[st] = __builtin_amdgcn_mfma_f32_32x32x16_bf16(ka, qf[0], zv, 0, 0, 0);
#pragma unroll
      for (int kc = 1; kc < 4; ++kc) {
        ka = *(const bf16x8*)(Kls + off[st][kc]);
        lgA[st] = __builtin_amdgcn_mfma_f32_32x32x16_bf16(ka, qf[kc], lgA[st],
                                                          0, 0, 0);
      }
    }
#pragma unroll
    for (int st = 0; st < 2; ++st) {
      const char* Kls = base + 8192;  // K_B
      bf16x8 ka = *(const bf16x8*)(Kls + off[st][0]);
      lgB[st] = __builtin_amdgcn_mfma_f32_32x32x16_bf16(ka, qf[0], zv, 0, 0, 0);
#pragma unroll
      for (int kc = 1; kc < 4; ++kc) {
        ka = *(const bf16x8*)(Kls + off[st][kc]);
        lgB[st] = __builtin_amdgcn_mfma_f32_32x32x16_bf16(ka, qf[kc], lgB[st],
                                                          0, 0, 0);
      }
    }

    // ---- SM + PV for sub-chunk A, then B (R9/R10-verified code x2) ----
#pragma unroll
    for (int sub = 0; sub < 2; ++sub) {
      f32x16* lg = sub ? lgB : lgA;
      const char* Vls = base + 16384 + sub * 8192;

      // online max: max3-shaped tree + permlane cross-half
      float w[11];
#pragma unroll
      for (int i = 0; i < 5; ++i)
        w[i] = fmaxf(fmaxf(lg[0][3 * i], lg[0][3 * i + 1]), lg[0][3 * i + 2]);
      w[5] = fmaxf(fmaxf(lg[0][15], lg[1][0]), lg[1][1]);
#pragma unroll
      for (int i = 0; i < 4; ++i)
        w[6 + i] = fmaxf(fmaxf(lg[1][3 * i + 2], lg[1][3 * i + 3]),
                         lg[1][3 * i + 4]);
      w[10] = fmaxf(lg[1][14], lg[1][15]);
      const float x0 = fmaxf(fmaxf(w[0], w[1]), w[2]);
      const float x1 = fmaxf(fmaxf(w[3], w[4]), w[5]);
      const float x2 = fmaxf(fmaxf(w[6], w[7]), w[8]);
      const float x3 = fmaxf(w[9], w[10]);
      float cm = fmax_x32(fmaxf(fmaxf(x0, x1), fmaxf(x2, x3)));
      if (!__all(cm <= mrun + 8.0f)) {   // deferred rescale, THR=8 (log2)
        const float nm = fmaxf(mrun, cm);
        const float fac = EXP2F(mrun - nm);
        mrun = nm;
        lsum *= fac;
#pragma unroll
        for (int cb = 0; cb < 2; ++cb)
#pragma unroll
          for (int r = 0; r < 16; ++r) acc[cb][r] *= fac;
      }

      // P = exp2(lg - m) in place; pairwise partial sum
      float ps = 0.f;
#pragma unroll
      for (int st = 0; st < 2; ++st) {
#pragma unroll
        for (int r = 0; r < 16; ++r) lg[st][r] = EXP2F(lg[st][r] - mrun);
#pragma unroll
        for (int r = 0; r < 8; ++r) ps += lg[st][2 * r] + lg[st][2 * r + 1];
      }
      lsum += ps;

      // pack + redistribute P -> PV fragments pa[ks] (R5-verified)
      bf16x8 pa[4];
#pragma unroll
      for (int st = 0; st < 2; ++st) {
#pragma unroll
        for (int kl = 0; kl < 2; ++kl) {
          const unsigned int p0a = pkbf(lg[st][8 * kl + 0], lg[st][8 * kl + 1]);
          const unsigned int p0b = pkbf(lg[st][8 * kl + 2], lg[st][8 * kl + 3]);
          const unsigned int p1a = pkbf(lg[st][8 * kl + 4], lg[st][8 * kl + 5]);
          const unsigned int p1b = pkbf(lg[st][8 * kl + 6], lg[st][8 * kl + 7]);
          const unsigned int sa = hi ? p0a : p1a;
          const unsigned int sb = hi ? p0b : p1b;
          const unsigned int ra = __shfl_xor(sa, 32);
          const unsigned int rb = __shfl_xor(sb, 32);
          union { unsigned int w[4]; bf16x8 v; } u;
          u.w[0] = hi ? ra : p0a;   // k-offsets 0,1
          u.w[1] = hi ? rb : p0b;   // 2,3
          u.w[2] = hi ? p1a : ra;   // 4,5
          u.w[3] = hi ? p1b : rb;   // 6,7
          pa[st * 2 + kl] = u.v;
        }
      }

      // PV: acc[cb] += V * P  (A = V rows=c, B = pa cols=t)
#pragma unroll
      for (int cb = 0; cb < 2; ++cb) {
#pragma unroll
        for (int ks = 0; ks < 4; ++ks) {
          const bf16x8 vb = *(const bf16x8*)(Vls + off[cb][ks]);
          acc[cb] = __builtin_amdgcn_mfma_f32_32x32x16_bf16(vb, pa[ks],
                                                            acc[cb], 0, 0, 0);
        }
      }
    }
  }

  // ---- epilogue: normalize + store (D: col=t=lane&31, row=c) ----
  const float ls = fadd_x32(lsum);
  const float inv = 1.0f / ls;
#pragma unroll
  for (int cb = 0; cb < 2; ++cb) {
#pragma unroll
    for (int r = 0; r < 16; ++r) {
      const int c = cb * 32 + (r & 3) + 8 * (r >> 2) + 4 * hi;
      out[((size_t)bh * 64 + c) * 2048 + t0w + tl] = acc[cb][r] * inv;
    }
  }
}

extern "C" void kernel_launch(void* const* d_in, const int* in_sizes, int n_in,
                              void* d_out, int out_size, void* d_ws,
                              size_t ws_size, hipStream_t stream) {
  (void)in_sizes; (void)n_in; (void)out_size;
  const float* qkv = (const float*)d_in[0];
  float* out = (float*)d_out;
  const size_t kv_elems = (size_t)64 * 2048 * 64;
  if (ws_size < kv_elems * 2 * sizeof(short)) return;  // need 32 MB scratch
  short* Kt = (short*)d_ws;
  short* Vb = Kt + kv_elems;
  hipLaunchKernelGGL(qkv_prep_kernel, dim3(2048), dim3(256), 0, stream,
                     qkv, Kt, Vb);
  hipLaunchKernelGGL(attn32_kernel, dim3(512), dim3(512), 0, stream,
                     qkv, Kt, Vb, out);
}

// Round 13
// 116.998 us; speedup vs baseline: 2.1686x; 1.1616x over previous
//
#include <hip/hip_runtime.h>
#include <hip/hip_bf16.h>
#include <cstdint>
#include <cstddef>

typedef short bf16x8 __attribute__((ext_vector_type(8)));
typedef float f32x16 __attribute__((ext_vector_type(16)));
typedef unsigned int uint2v __attribute__((ext_vector_type(2)));

// scale^2 * log2(e) folded into Q; ch=64 -> (1/8)*1.4426950408889634
#define QSCALE 0.18033688011112043f

__device__ __forceinline__ short f2bf(float f) {
  union { __hip_bfloat16 b; short s; } u;
  u.b = __float2bfloat16(f);
  return u.s;
}

// 2^x as ONE transcendental instruction (VALU-interlocked, no waitcnt).
__device__ __forceinline__ float exp2v(float x) {
  float r;
  asm("v_exp_f32 %0, %1" : "=v"(r) : "v"(x));
  return r;
}

// packed f32x2 -> bf16x2 RNE via the header intrinsic (defined ordering:
// a -> low 16, b -> high 16; compiles to v_cvt_pk_bf16_f32 on gfx950)
__device__ __forceinline__ unsigned int packbf2(float a, float b) {
  union { __hip_bfloat162 h; unsigned int w; } u;
  u.h = __float22bfloat162_rn(float2{a, b});
  return u.w;
}

__device__ __forceinline__ unsigned int fbits(float f) {
  union { float f; unsigned int u; } x; x.f = f; return x.u;
}
__device__ __forceinline__ float bfloat(unsigned int u) {
  union { unsigned int u; float f; } x; x.u = u; return x.f;
}

// permlane32_swap builtin — ONLY for commutative own+partner combines
// (correct under any half-swap convention; results contain {own,partner})
__device__ __forceinline__ float fmax_x32(float v) {
  const uint2v r = __builtin_amdgcn_permlane32_swap(fbits(v), fbits(v),
                                                    false, false);
  return fmaxf(bfloat(r[0]), bfloat(r[1]));
}
__device__ __forceinline__ float fadd_x32(float v) {
  const uint2v r = __builtin_amdgcn_permlane32_swap(fbits(v), fbits(v),
                                                    false, false);
  return bfloat(r[0]) + bfloat(r[1]);
}

// async global -> LDS, 16 B per lane; LDS dest = wave-uniform base + lane*16
__device__ __forceinline__ void gload16(const short* g, char* l) {
  __builtin_amdgcn_global_load_lds(
      (const __attribute__((address_space(1))) void*)g,
      (__attribute__((address_space(3))) void*)l, 16, 0, 0);
}

// ---------------------------------------------------------------------------
// Prepass: Kt[bh][s][c] = bf16(K[c][s]);  Vb[bh][c][s] = bf16(V[c][s]).
// qkv layout: [bh][cc][t], cc: 0..63 Q, 64..127 K, 128..191 V.
// ---------------------------------------------------------------------------
__global__ __launch_bounds__(256, 4) void qkv_prep_kernel(
    const float* __restrict__ qkv, short* __restrict__ Kt,
    short* __restrict__ Vb) {
  const int bh = blockIdx.x >> 5;
  const int s0 = (blockIdx.x & 31) << 6;
  const int tid = threadIdx.x;
  const int row = tid >> 2;   // 0..63
  const int part = tid & 3;   // 0..3  (16 columns each)
  __shared__ float lds[64 * 65];

  const size_t qb = (size_t)bh * (192 * 2048);

  // ---- K: load [c][s] tile coalesced into LDS ----
  {
    const float* src = qkv + qb + (size_t)(64 + row) * 2048 + s0 + part * 16;
#pragma unroll
    for (int k4 = 0; k4 < 4; ++k4) {
      float4 v = ((const float4*)src)[k4];
      float* p = &lds[row * 65 + part * 16 + k4 * 4];
      p[0] = v.x; p[1] = v.y; p[2] = v.z; p[3] = v.w;
    }
  }
  __syncthreads();
  // ---- transposed read -> Kt[s][c], coalesced 16B stores ----
  {
    bf16x8 o0, o1;
#pragma unroll
    for (int k = 0; k < 8; ++k) o0[k] = f2bf(lds[(part * 16 + k) * 65 + row]);
#pragma unroll
    for (int k = 0; k < 8; ++k) o1[k] = f2bf(lds[(part * 16 + 8 + k) * 65 + row]);
    short* dst = Kt + ((size_t)bh * 2048 + s0 + row) * 64 + part * 16;
    *(bf16x8*)dst = o0;
    *(bf16x8*)(dst + 8) = o1;
  }
  // ---- V: straight convert, both sides coalesced ----
  {
    const float* src = qkv + qb + (size_t)(128 + row) * 2048 + s0 + part * 16;
    float a[16];
#pragma unroll
    for (int k4 = 0; k4 < 4; ++k4) {
      float4 v = ((const float4*)src)[k4];
      a[k4 * 4 + 0] = v.x; a[k4 * 4 + 1] = v.y;
      a[k4 * 4 + 2] = v.z; a[k4 * 4 + 3] = v.w;
    }
    bf16x8 o0, o1;
#pragma unroll
    for (int k = 0; k < 8; ++k) { o0[k] = f2bf(a[k]); o1[k] = f2bf(a[8 + k]); }
    short* dst = Vb + ((size_t)bh * 64 + row) * 2048 + s0 + part * 16;
    *(bf16x8*)dst = o0;
    *(bf16x8*)(dst + 8) = o1;
  }
}

// ---------------------------------------------------------------------------
// Flash attention = R10-verified structure, with two single-instruction
// substitutions in the softmax inner loop (v_exp_f32 asm; cvt_pk pack).
// 512 blocks (XCD-swizzled), 8 waves, wave owns 32 t; s-chunks of 64;
// K/V LDS dbuf, gload_lds with pre-swizzled source; one barrier per chunk.
// ---------------------------------------------------------------------------
__global__ __launch_bounds__(512, 4) void attn32_kernel(
    const float* __restrict__ qkv, const short* __restrict__ Kt,
    const short* __restrict__ Vb, float* __restrict__ out) {
  const int bid = blockIdx.x;
  const int vid = (bid & 7) * 64 + (bid >> 3);  // bijective XCD swizzle (512)
  const int bh = vid >> 3;
  const int tblk = vid & 7;
  const int tid = threadIdx.x;
  const int wv = tid >> 6;          // 0..7
  const int lane = tid & 63;
  const int tl = lane & 31;
  const int hi = lane >> 5;
  const int t0w = tblk * 256 + wv * 32;

  // [buf0: K 8K | V 8K][buf1: K 8K | V 8K]
  __shared__ __align__(16) char smem[32768];

  // ---- Q fragments (B-operand: col = t = lane&31, k = kc*16 + hi*8 + j) ----
  const size_t qb = (size_t)bh * (192 * 2048);
  bf16x8 qf[4];
#pragma unroll
  for (int kc = 0; kc < 4; ++kc) {
#pragma unroll
    for (int j = 0; j < 8; ++j) {
      const int c = kc * 16 + hi * 8 + j;
      qf[kc][j] = f2bf(qkv[qb + (size_t)c * 2048 + t0w + tl] * QSCALE);
    }
  }

  // persistent zero C-operand (avoids per-chunk zero-init movs)
  f32x16 zv;
#pragma unroll
  for (int r = 0; r < 16; ++r) zv[r] = 0.f;

  f32x16 acc[2];
#pragma unroll
  for (int cb = 0; cb < 2; ++cb) acc[cb] = zv;

  float mrun = -1e30f;
  float lsum = 0.f;

  // ---- hoisted LDS read offsets: one table serves QK (rows=s) and PV
  // (rows=c): off[x][j] = (x*32+tl)*128 + ((j*32+hi*16) ^ rsw) ----
  const int rsw = (tl & 7) * 16;
  int off[2][4];
#pragma unroll
  for (int x = 0; x < 2; ++x)
#pragma unroll
    for (int j = 0; j < 4; ++j)
      off[x][j] = (x * 32 + tl) * 128 + ((j * 32 + hi * 16) ^ rsw);

  // ---- staging geometry: 512 threads cover all 64 rows in one pass ----
  const int srow = tid >> 3;   // 0..63
  const int sl = tid & 7;      // 16B slot within 128B row
  // pre-swizzled global sources (slot ^ (row&7)); involution matches reads
  const short* kg = Kt + (size_t)bh * (2048 * 64) + (size_t)srow * 64 +
                    ((sl ^ (srow & 7)) * 8);
  const short* vg = Vb + ((size_t)bh * 64 + srow) * 2048 +
                    ((sl ^ (srow & 7)) * 8);
  // wave-uniform LDS byte offset (lane*16 added by HW):
  // wave wv covers rows [wv*8, wv*8+8): base = wv*8*128 = wv*1024
  const int ldb = wv * 1024;

  // ---- prologue: stage chunk 0 into buf0 ----
  gload16(kg, smem + ldb);
  gload16(vg, smem + 8192 + ldb);

#pragma unroll 2
  for (int ch = 0; ch < 32; ++ch) {
    char* const Kls = smem + (ch & 1) * 16384;
    char* const Vls = Kls + 8192;

    // barrier: (a) all waves done reading buf^1, (b) vmcnt(0) inside the
    // barrier drains this chunk's prefetch -> buf ready
    __syncthreads();

    // ---- issue next chunk's staging; flies under this chunk's compute ----
    if (ch < 31) {
      char* const Knx = smem + ((ch + 1) & 1) * 16384;
      gload16(kg + (size_t)(ch + 1) * 4096, Knx + ldb);        // 64 rows x 64c
      gload16(vg + (ch + 1) * 64, Knx + 8192 + ldb);           // 64 s along row
    }

    // ---- QK^T: two 32-s tiles, A = K (rows=s), B = Q (cols=t) ----
    f32x16 lg[2];
#pragma unroll
    for (int st = 0; st < 2; ++st) {
      bf16x8 ka = *(const bf16x8*)(Kls + off[st][0]);
      lg[st] = __builtin_amdgcn_mfma_f32_32x32x16_bf16(ka, qf[0], zv, 0, 0, 0);
#pragma unroll
      for (int kc = 1; kc < 4; ++kc) {
        ka = *(const bf16x8*)(Kls + off[st][kc]);
        lg[st] = __builtin_amdgcn_mfma_f32_32x32x16_bf16(ka, qf[kc], lg[st],
                                                         0, 0, 0);
      }
    }

    // ---- online max: max3-shaped tree + permlane cross-half ----
    float w[11];
#pragma unroll
    for (int i = 0; i < 5; ++i)
      w[i] = fmaxf(fmaxf(lg[0][3 * i], lg[0][3 * i + 1]), lg[0][3 * i + 2]);
    w[5] = fmaxf(fmaxf(lg[0][15], lg[1][0]), lg[1][1]);
#pragma unroll
    for (int i = 0; i < 4; ++i)
      w[6 + i] = fmaxf(fmaxf(lg[1][3 * i + 2], lg[1][3 * i + 3]),
                       lg[1][3 * i + 4]);
    w[10] = fmaxf(lg[1][14], lg[1][15]);
    const float x0 = fmaxf(fmaxf(w[0], w[1]), w[2]);
    const float x1 = fmaxf(fmaxf(w[3], w[4]), w[5]);
    const float x2 = fmaxf(fmaxf(w[6], w[7]), w[8]);
    const float x3 = fmaxf(w[9], w[10]);
    float cm = fmax_x32(fmaxf(fmaxf(x0, x1), fmaxf(x2, x3)));
    if (!__all(cm <= mrun + 8.0f)) {   // deferred rescale, THR=8 (log2)
      const float nm = fmaxf(mrun, cm);
      const float fac = exp2v(mrun - nm);
      mrun = nm;
      lsum *= fac;
#pragma unroll
      for (int cb = 0; cb < 2; ++cb)
#pragma unroll
        for (int r = 0; r < 16; ++r) acc[cb][r] *= fac;
    }

    // ---- P = exp2(lg - m) in place; pairwise partial sum ----
    float ps = 0.f;
#pragma unroll
    for (int st = 0; st < 2; ++st) {
#pragma unroll
      for (int r = 0; r < 16; ++r) lg[st][r] = exp2v(lg[st][r] - mrun);
#pragma unroll
      for (int r = 0; r < 8; ++r) ps += lg[st][2 * r] + lg[st][2 * r + 1];
    }
    lsum += ps;

    // ---- pack + redistribute P -> PV fragments pa[ks] (R5-verified) ----
    bf16x8 pa[4];
#pragma unroll
    for (int st = 0; st < 2; ++st) {
#pragma unroll
      for (int kl = 0; kl < 2; ++kl) {
        const unsigned int p0a = packbf2(lg[st][8 * kl + 0], lg[st][8 * kl + 1]);
        const unsigned int p0b = packbf2(lg[st][8 * kl + 2], lg[st][8 * kl + 3]);
        const unsigned int p1a = packbf2(lg[st][8 * kl + 4], lg[st][8 * kl + 5]);
        const unsigned int p1b = packbf2(lg[st][8 * kl + 6], lg[st][8 * kl + 7]);
        const unsigned int sa = hi ? p0a : p1a;
        const unsigned int sb = hi ? p0b : p1b;
        const unsigned int ra = __shfl_xor(sa, 32);
        const unsigned int rb = __shfl_xor(sb, 32);
        union { unsigned int w[4]; bf16x8 v; } u;
        u.w[0] = hi ? ra : p0a;   // k-offsets 0,1
        u.w[1] = hi ? rb : p0b;   // 2,3
        u.w[2] = hi ? p1a : ra;   // 4,5
        u.w[3] = hi ? p1b : rb;   // 6,7
        pa[st * 2 + kl] = u.v;
      }
    }

    // ---- PV: acc[cb] += V * P  (A = V rows=c, B = pa cols=t) ----
#pragma unroll
    for (int cb = 0; cb < 2; ++cb) {
#pragma unroll
      for (int ks = 0; ks < 4; ++ks) {
        const bf16x8 vb = *(const bf16x8*)(Vls + off[cb][ks]);
        acc[cb] = __builtin_amdgcn_mfma_f32_32x32x16_bf16(vb, pa[ks], acc[cb],
                                                          0, 0, 0);
      }
    }
  }

  // ---- epilogue: normalize + store (D: col=t=lane&31, row=c) ----
  const float ls = fadd_x32(lsum);
  const float inv = 1.0f / ls;
#pragma unroll
  for (int cb = 0; cb < 2; ++cb) {
#pragma unroll
    for (int r = 0; r < 16; ++r) {
      const int c = cb * 32 + (r & 3) + 8 * (r >> 2) + 4 * hi;
      out[((size_t)bh * 64 + c) * 2048 + t0w + tl] = acc[cb][r] * inv;
    }
  }
}

extern "C" void kernel_launch(void* const* d_in, const int* in_sizes, int n_in,
                              void* d_out, int out_size, void* d_ws,
                              size_t ws_size, hipStream_t stream) {
  (void)in_sizes; (void)n_in; (void)out_size;
  const float* qkv = (const float*)d_in[0];
  float* out = (float*)d_out;
  const size_t kv_elems = (size_t)64 * 2048 * 64;
  if (ws_size < kv_elems * 2 * sizeof(short)) return;  // need 32 MB scratch
  short* Kt = (short*)d_ws;
  short* Vb = Kt + kv_elems;
  hipLaunchKernelGGL(qkv_prep_kernel, dim3(2048), dim3(256), 0, stream,
                     qkv, Kt, Vb);
  hipLaunchKernelGGL(attn32_kernel, dim3(512), dim3(512), 0, stream,
                     qkv, Kt, Vb, out);
}